// Round 8
// baseline (174.718 us; speedup 1.0000x reference)
//
#include <hip/hip_runtime.h>
#include <math.h>

#define TBD 8
#define CD  512
#define ND  512
#define PLANE (TBD*CD*ND)   // 2,097,152 elems (u16) per plane
#define WPL   (CD*CD)

typedef unsigned short u16;
typedef unsigned int u32;
typedef _Float16 f16;
typedef __attribute__((ext_vector_type(8))) short bf16x8;
typedef __attribute__((ext_vector_type(8))) _Float16 f16x8;
typedef __attribute__((ext_vector_type(4))) float f32x4;
typedef __attribute__((ext_vector_type(16))) float f32x16;

__device__ __forceinline__ float b2f(u16 u){
  union{u32 i; float f;} x; x.i = ((u32)u) << 16; return x.f;
}
__device__ __forceinline__ u16 f2b(float f){
  u32 u = __builtin_bit_cast(u32, f);
  u += 0x7fffu + ((u >> 16) & 1u);
  return (u16)(u >> 16);
}
__device__ __forceinline__ void async_ld16(const void* g, void* l){
  __builtin_amdgcn_global_load_lds((const __attribute__((address_space(1))) u32*)g,
      (__attribute__((address_space(3))) u32*)l, 16, 0, 0);
}

// ---------------------------------------------------------------------------
// prep (r3..r7-proven, unchanged)
// ---------------------------------------------------------------------------
__global__ __launch_bounds__(256) void prep(
    const float* __restrict__ x, const float* __restrict__ y,
    const float* __restrict__ Qw, const float* __restrict__ Kw,
    const float* __restrict__ Vw, const float* __restrict__ Pw,
    const float* __restrict__ Qg, const float* __restrict__ Qb, const float* __restrict__ Qm, const float* __restrict__ Qv,
    const float* __restrict__ Kg, const float* __restrict__ Kb, const float* __restrict__ Km, const float* __restrict__ Kv,
    const float* __restrict__ Vg, const float* __restrict__ Vb, const float* __restrict__ Vm, const float* __restrict__ Vv,
    const float* __restrict__ Pg, const float* __restrict__ Pb, const float* __restrict__ Pm, const float* __restrict__ Pv,
    u16* __restrict__ wsu, float* __restrict__ ib)
{
  const int bx = blockIdx.x, t = threadIdx.x;
  if (bx < 1024) {
    __shared__ __align__(16) float tl[64][68];
    const int inp = bx >> 9, rem = bx & 511;
    const int tb = rem >> 6, tile = rem & 63;
    const int ct = (tile & 7) << 6, nt = (tile >> 3) << 6;
    const float* xg = inp ? y : x;
    #pragma unroll
    for (int r = 0; r < 4; ++r) {
      const int row = (t >> 4) + (r << 4);
      const int col = (t & 15) << 2;
      *(float4*)&tl[row][col] =
          *(const float4*)(xg + ((size_t)(tb*CD + ct + row))*ND + nt + col);
    }
    __syncthreads();
    const int nl = t >> 2, cb = (t & 3) << 4;
    __align__(16) u16 h[3][16];
    #pragma unroll
    for (int j = 0; j < 16; ++j) {
      const float f = tl[cb + j][nl];
      const u16 a = f2b(f);  const float r1 = f - b2f(a);
      const u16 b = f2b(r1); const float r2 = r1 - b2f(b);
      h[0][j] = a; h[1][j] = b; h[2][j] = f2b(r2);
    }
    u16* base = wsu + (size_t)inp*3*PLANE;
    const size_t rowo = ((size_t)tb*ND + nt + nl)*CD + ct + cb;
    #pragma unroll
    for (int s = 0; s < 3; ++s) {
      *(uint4*)(base + (size_t)s*PLANE + rowo)     = *(uint4*)&h[s][0];
      *(uint4*)(base + (size_t)s*PLANE + rowo + 8) = *(uint4*)&h[s][8];
    }
  } else if (bx < 2048) {
    const int b2 = bx - 1024;
    const int mat = b2 >> 8, rr = b2 & 255;
    const float* Wg = (mat==0)?Qw:(mat==1)?Kw:(mat==2)?Vw:Pw;
    const int row = (rr << 1) + (t >> 7);
    const int col = (t & 127) << 2;
    const float4 w = *(const float4*)(Wg + (size_t)row*CD + col);
    const float f[4] = {w.x, w.y, w.z, w.w};
    __align__(8) u16 h[3][4];
    #pragma unroll
    for (int j = 0; j < 4; ++j) {
      const u16 a = f2b(f[j]);  const float r1 = f[j] - b2f(a);
      const u16 b = f2b(r1);    const float r2 = r1 - b2f(b);
      h[0][j] = a; h[1][j] = b; h[2][j] = f2b(r2);
    }
    u16* base = wsu + (size_t)6*PLANE + (size_t)mat*3*WPL;
    #pragma unroll
    for (int s = 0; s < 3; ++s)
      *(uint2*)(base + (size_t)s*WPL + (size_t)row*CD + col) = *(uint2*)&h[s][0];
  } else {
    const int idx = (bx - 2048)*256 + t;
    const int br = idx >> 9, ch = idx & 511;
    const float* G = (br==0)?Qg:(br==1)?Kg:(br==2)?Vg:Pg;
    const float* B = (br==0)?Qb:(br==1)?Kb:(br==2)?Vb:Pb;
    const float* M = (br==0)?Qm:(br==1)?Km:(br==2)?Vm:Pm;
    const float* V = (br==0)?Qv:(br==1)?Kv:(br==2)?Vv:Pv;
    const float inv = G[ch] / sqrtf(V[ch] + 1e-5f);
    ib[br*1024 + ch]       = inv;
    ib[br*1024 + 512 + ch] = B[ch] - M[ch]*inv;
  }
}

// ---------------------------------------------------------------------------
// qkv split-bf16 GEMM + BN + LIF — r5 staging/structure, inner loop switched
// to v_mfma_f32_32x32x16_bf16 (4061 vs 3378 FLOP/cyc, half the MFMA issue
// slots). Wave tile stays 32x32; the 32-row A/B fragment (m=lane&31,
// k=(lane>>5)*8+j) spans two adjacent 16-row staging tiles (tile stride
// 512 u16 = 0 mod 32 banks -> uniform 8 words/bank = b128 minimum).
// Two accumulators split by k-half for MFMA ILP; summed in epilogue
// (fp32 reassociation of exact bf16 products — proven-safe class).
// C/D layout (m74/m101 HW-verified): col=lane&31, row=(reg&3)+8*(reg>>2)
// +4*(lane>>5).
// ---------------------------------------------------------------------------
__global__ __launch_bounds__(256) void gemm_qkv(
    const u16* __restrict__ Ab, const u16* __restrict__ Bbp,
    const float* __restrict__ ibp, u16* __restrict__ spk)
{
  const int bx  = blockIdx.x;
  const int idx = bx & 511;
  const int br  = bx >> 9;
  const int tb  = idx & 7;
  const int o0  = ((idx >> 3) & 7) << 6;
  const int n0  = (idx >> 6) << 6;
  const int t    = threadIdx.x;
  const int lane = t & 63, wave = t >> 6;

  const u16* A = Ab + (size_t)br*3*WPL;
  const u16* B = Bbp + (size_t)(br ? 3 : 0)*PLANE;
  const float* IB = ibp + br*1024;

  __shared__ __align__(16) u16 smem[2*3*4*512 + 2*3*4*512];   // 48 KB
  u16* Al = smem;
  u16* Bl = smem + 2*3*4*512;

  const int lr = lane >> 2;
  const int lc = ((lane & 3) ^ ((lane >> 3) & 3)) << 3;

  auto stage = [&](int buf, int c0) {
    #pragma unroll
    for (int j = 0; j < 6; ++j) {
      const int tix = wave*6 + j;
      if (tix < 12) {
        const int s = tix >> 2, ot = tix & 3;
        async_ld16(A + (size_t)s*WPL + (size_t)(o0 + (ot<<4) + lr)*CD + c0 + lc,
                   Al + (((buf*3 + s)*4 + ot) << 9) + (lane << 3));
      } else {
        const int k = tix - 12, s = k >> 2, nt = k & 3;
        async_ld16(B + (size_t)s*PLANE + ((size_t)tb*ND + n0 + (nt<<4) + lr)*CD + c0 + lc,
                   Bl + (((buf*3 + s)*4 + nt) << 9) + (lane << 3));
      }
    }
  };

  f32x16 acc0 = {}, acc1 = {};

  const int otb = (wave >> 1) << 1;        // wave's base 16-row tile in o
  const int ntb = (wave & 1) << 1;         // wave's base 16-row tile in n
  // 32-row fragment addressing over two 16-row staging tiles:
  const int rA   = lane & 15;
  const int tsel = (lane >> 4) & 1;        // which 16-row tile
  const int kbl  = lane >> 5;              // k-block within k-half
  const int key  = (lane >> 1) & 3;        // XOR swizzle key (bits of rA)
  const int foh0 = (rA << 5) + (((kbl + 0) ^ key) << 3);   // k-half 0
  const int foh1 = (rA << 5) + ((((kbl + 2) ^ key) & 3) << 3); // k-half 1

  stage(0, 0);
  for (int i = 0; i < 16; ++i) {
    const int buf = i & 1;
    __syncthreads();
    if (i < 15) stage(buf ^ 1, (i + 1) << 5);

    bf16x8 Af[3][2], Bf[3][2];
    #pragma unroll
    for (int s = 0; s < 3; ++s) {
      const int ta = ((buf*3 + s)*4 + otb + tsel) << 9;
      Af[s][0] = *(const bf16x8*)(Al + ta + foh0);
      Af[s][1] = *(const bf16x8*)(Al + ta + foh1);
      const int tbq = ((buf*3 + s)*4 + ntb + tsel) << 9;
      Bf[s][0] = *(const bf16x8*)(Bl + tbq + foh0);
      Bf[s][1] = *(const bf16x8*)(Bl + tbq + foh1);
    }

    auto mm = [&](int sa, int sb) {
      acc0 = __builtin_amdgcn_mfma_f32_32x32x16_bf16(Af[sa][0], Bf[sb][0], acc0, 0, 0, 0);
      acc1 = __builtin_amdgcn_mfma_f32_32x32x16_bf16(Af[sa][1], Bf[sb][1], acc1, 0, 0, 0);
    };
    mm(0,0); mm(0,1); mm(1,0); mm(1,1); mm(0,2); mm(2,0);
  }

  // epilogue: BN + LIF, 32x32 C layout (m74/m101)
  const int colN   = n0 + ((wave & 1) << 5) + (lane & 31);
  const int rbase2 = (lane >> 5) << 2;
  u16* outp = spk + (size_t)br*PLANE + (size_t)tb*CD*ND;
  #pragma unroll
  for (int reg = 0; reg < 16; ++reg) {
    const int row = (reg & 3) + ((reg >> 2) << 3) + rbase2;
    const int ch  = o0 + ((wave >> 1) << 5) + row;
    const float v = acc0[reg] + acc1[reg];
    const bool sp = (v * IB[ch] + IB[512 + ch] >= 2.0f);
    outp[(size_t)ch*ND + colN] = sp ? (u16)0x3C00 : (u16)0;
  }
}

// ---------------------------------------------------------------------------
// MFMA attention (r5..r7-proven, unchanged).
// ---------------------------------------------------------------------------
__global__ __launch_bounds__(256) void attn(
    const u16* __restrict__ Qs, const u16* __restrict__ Ks,
    const u16* __restrict__ Vs, u16* __restrict__ S2T)
{
  const int tbh = blockIdx.x >> 2;
  const int n0  = (blockIdx.x & 3) << 7;
  const int t = threadIdx.x, lane = t & 63, wave = t >> 6;
  const int tb = tbh >> 4, h = tbh & 15;

  __shared__ __align__(16) u16 Kt[2*8*512];
  __shared__ __align__(16) u16 Vt[2*8*512];
  __shared__ __align__(16) u16 Qg[8*520];
  __shared__ __align__(16) u16 Gt[4*32*40];
  __shared__ __align__(16) u16 Sb[128*40];

  const u16* Kh = Ks + (size_t)tbh*32*ND;
  const u16* Vh = Vs + (size_t)tbh*32*ND;
  const u16* Qh = Qs + (size_t)tbh*32*ND;

  const int lr = lane >> 2;
  const int lc = ((lane & 3) ^ ((lane >> 3) & 3)) << 3;
  const int fo = ((lane & 15) << 5) + ((((lane >> 4) ^ ((lane >> 1) & 3)) & 3) << 3);

  f32x4 g[2][2];
  const f32x4 zero = {0.f, 0.f, 0.f, 0.f};
  g[0][0] = zero; g[0][1] = zero; g[1][0] = zero; g[1][1] = zero;

  for (int half = 0; half < 2; ++half) {
    if (half) __syncthreads();
    #pragma unroll
    for (int j = 0; j < 8; ++j) {
      const int u = wave*8 + j;
      const int mat = u >> 4, dt = (u >> 3) & 1, kc = u & 7;
      const u16* src = (mat ? Vh : Kh) + (size_t)((dt << 4) + lr)*ND + (half << 8) + (kc << 5) + lc;
      u16* dst = (mat ? Vt : Kt) + (((dt << 3) + kc) << 9) + (lane << 3);
      async_ld16(src, dst);
    }
    if (half == 0) {
      #pragma unroll
      for (int j = 0; j < 2; ++j) {
        const int gq = wave*2 + j;
        async_ld16(Qh + (size_t)((gq << 2) + (lane >> 4))*ND + n0 + ((lane & 15) << 3),
                   Qg + gq*520 + (lane << 3));
      }
    }
    __syncthreads();
    for (int kc = 0; kc < 8; ++kc) {
      const f16* kt = (const f16*)Kt;
      const f16* vt = (const f16*)Vt;
      f16x8 ka0 = *(const f16x8*)(kt + (kc << 9) + fo);
      f16x8 ka1 = *(const f16x8*)(kt + ((8 + kc) << 9) + fo);
      f16x8 vb0 = *(const f16x8*)(vt + (kc << 9) + fo);
      f16x8 vb1 = *(const f16x8*)(vt + ((8 + kc) << 9) + fo);
      g[0][0] = __builtin_amdgcn_mfma_f32_16x16x32_f16(ka0, vb0, g[0][0], 0,0,0);
      g[0][1] = __builtin_amdgcn_mfma_f32_16x16x32_f16(ka0, vb1, g[0][1], 0,0,0);
      g[1][0] = __builtin_amdgcn_mfma_f32_16x16x32_f16(ka1, vb0, g[1][0], 0,0,0);
      g[1][1] = __builtin_amdgcn_mfma_f32_16x16x32_f16(ka1, vb1, g[1][1], 0,0,0);
    }
  }

  f16* myG = (f16*)(Gt + wave*(32*40));
  const int rq = (lane >> 4) << 2, cl = lane & 15;
  #pragma unroll
  for (int d1t = 0; d1t < 2; ++d1t)
    #pragma unroll
    for (int d2t = 0; d2t < 2; ++d2t)
      #pragma unroll
      for (int r = 0; r < 4; ++r) {
        const int d1 = (d1t << 4) + rq + r;
        const int d2 = (d2t << 4) + cl;
        myG[d2*40 + d1] = (f16)g[d1t][d2t][r];
      }
  asm volatile("s_waitcnt lgkmcnt(0)" ::: "memory");

  f32x4 o[2][2];
  o[0][0] = zero; o[0][1] = zero; o[1][0] = zero; o[1][1] = zero;
  const f16* ql = (const f16*)Qg;
  const int kg = lane >> 4, n16 = lane & 15;
  #pragma unroll
  for (int ntl = 0; ntl < 2; ++ntl) {
    const int n0w = ((wave << 1) + ntl) << 4;
    f16x8 qb;
    #pragma unroll
    for (int j = 0; j < 8; ++j)
      qb[j] = ql[(2*kg + (j >> 2))*520 + (j & 3)*128 + n0w + n16];
    #pragma unroll
    for (int dd = 0; dd < 2; ++dd) {
      f16x8 ga = *(const f16x8*)(myG + (((dd << 4) + cl)*40) + (kg << 3));
      o[dd][ntl] = __builtin_amdgcn_mfma_f32_16x16x32_f16(ga, qb, o[dd][ntl], 0,0,0);
    }
  }

  #pragma unroll
  for (int dd = 0; dd < 2; ++dd)
    #pragma unroll
    for (int ntl = 0; ntl < 2; ++ntl)
      #pragma unroll
      for (int r = 0; r < 4; ++r) {
        const int n_local = ((wave*2 + ntl) << 4) + cl;
        const int c_local = (dd << 4) + rq + r;
        Sb[n_local*40 + c_local] = (o[dd][ntl][r] >= 8.0f) ? (u16)0x3F80 : (u16)0;
      }
  asm volatile("s_waitcnt lgkmcnt(0)" ::: "memory");

  const int nr = (wave << 5) + (lane >> 1);
  const int cs = (lane & 1) << 4;
  u16* dst = S2T + ((size_t)tb*ND + n0 + nr)*CD + (h << 5) + cs;
  *(uint4*)dst       = *(uint4*)&Sb[nr*40 + cs];
  *(uint4*)(dst + 8) = *(uint4*)&Sb[nr*40 + cs + 8];
}

// ---------------------------------------------------------------------------
// Final gemm, BK=64 staging (r6-proven) with 32x32x16 inner loop.
// ---------------------------------------------------------------------------
__global__ __launch_bounds__(256) void gemm_p(
    const u16* __restrict__ Ab, const u16* __restrict__ Bb,
    const float* __restrict__ IB, float* __restrict__ outf)
{
  const int idx = blockIdx.x;
  const int tb  = idx & 7;
  const int o0  = ((idx >> 3) & 7) << 6;
  const int n0  = (idx >> 6) << 6;
  const int t    = threadIdx.x;
  const int lane = t & 63, wave = t >> 6;

  __shared__ __align__(16) u16 smem[2*32*512];   // 64 KB

  const int lr = lane >> 2;
  const int lc = ((lane & 3) ^ ((lane >> 3) & 3)) << 3;
  const int otb = (wave >> 1) << 1;
  const int ntb = (wave & 1) << 1;
  const int rA   = lane & 15;
  const int tsel = (lane >> 4) & 1;
  const int kbl  = lane >> 5;
  const int key  = (lane >> 1) & 3;
  const int foh0 = (rA << 5) + (((kbl + 0) ^ key) << 3);
  const int foh1 = (rA << 5) + ((((kbl + 2) ^ key) & 3) << 3);

  auto stage = [&](int buf, int c0) {
    #pragma unroll
    for (int j = 0; j < 8; ++j) {
      const int tix  = wave*8 + j;
      const int ksub = tix >> 4, slot = tix & 15;
      const int cc = c0 + (ksub << 5);
      const u16* g;
      if (slot < 12) {
        const int s = slot >> 2, ot = slot & 3;
        g = Ab + (size_t)s*WPL + (size_t)(o0 + (ot<<4) + lr)*CD + cc + lc;
      } else {
        const int nt = slot - 12;
        g = Bb + ((size_t)tb*ND + n0 + (nt<<4) + lr)*CD + cc + lc;
      }
      async_ld16(g, smem + (((size_t)buf*32 + tix) << 9) + (lane << 3));
    }
  };

  f32x16 acc0 = {}, acc1 = {};

  stage(0, 0);
  for (int i = 0; i < 8; ++i) {
    const int buf = i & 1;
    __syncthreads();
    if (i < 7) stage(buf ^ 1, (i + 1) << 6);

    #pragma unroll
    for (int ksub = 0; ksub < 2; ++ksub) {
      const int base = (buf*32 + ksub*16) << 9;
      bf16x8 Af[3][2], Bf[2];
      #pragma unroll
      for (int s = 0; s < 3; ++s) {
        const int ta = base + ((s*4 + otb + tsel) << 9);
        Af[s][0] = *(const bf16x8*)(smem + ta + foh0);
        Af[s][1] = *(const bf16x8*)(smem + ta + foh1);
      }
      const int tbq = base + ((12 + ntb + tsel) << 9);
      Bf[0] = *(const bf16x8*)(smem + tbq + foh0);
      Bf[1] = *(const bf16x8*)(smem + tbq + foh1);

      #pragma unroll
      for (int s = 0; s < 3; ++s) {
        acc0 = __builtin_amdgcn_mfma_f32_32x32x16_bf16(Af[s][0], Bf[0], acc0, 0, 0, 0);
        acc1 = __builtin_amdgcn_mfma_f32_32x32x16_bf16(Af[s][1], Bf[1], acc1, 0, 0, 0);
      }
    }
  }

  const int colN   = n0 + ((wave & 1) << 5) + (lane & 31);
  const int rbase2 = (lane >> 5) << 2;
  float* outp = outf + (size_t)tb*CD*ND;
  #pragma unroll
  for (int reg = 0; reg < 16; ++reg) {
    const int row = (reg & 3) + ((reg >> 2) << 3) + rbase2;
    const int ch  = o0 + ((wave >> 1) << 5) + row;
    const float v = acc0[reg] + acc1[reg];
    const bool sp = (v * IB[ch] + IB[512 + ch] >= 2.0f);
    outp[(size_t)ch*ND + colN] = sp ? 1.0f : 0.0f;
  }
}

// ---------------------------------------------------------------------------
extern "C" void kernel_launch(void* const* d_in, const int* in_sizes, int n_in,
                              void* d_out, int out_size, void* d_ws, size_t ws_size,
                              hipStream_t stream)
{
  const float* x  = (const float*)d_in[0];
  const float* y  = (const float*)d_in[1];
  const float* qw = (const float*)d_in[2];
  const float* qg = (const float*)d_in[3];
  const float* qb = (const float*)d_in[4];
  const float* qm = (const float*)d_in[5];
  const float* qv = (const float*)d_in[6];
  const float* kw = (const float*)d_in[7];
  const float* kg = (const float*)d_in[8];
  const float* kb = (const float*)d_in[9];
  const float* km = (const float*)d_in[10];
  const float* kv = (const float*)d_in[11];
  const float* vw = (const float*)d_in[12];
  const float* vg = (const float*)d_in[13];
  const float* vb = (const float*)d_in[14];
  const float* vm = (const float*)d_in[15];
  const float* vv = (const float*)d_in[16];
  const float* pw = (const float*)d_in[17];
  const float* pg = (const float*)d_in[18];
  const float* pb = (const float*)d_in[19];
  const float* pm = (const float*)d_in[20];
  const float* pv = (const float*)d_in[21];

  u16* wsu = (u16*)d_ws;
  // layout (u16): xS[3] | yS[3] | W[4][3] | Q,K,V spikes [c][n] | S2T | ib
  u16* Wq   = wsu + (size_t)6*PLANE;
  u16* SPK  = wsu + (size_t)6*PLANE + 12*WPL;
  u16* S2T  = SPK + (size_t)3*PLANE;
  float* ib = (float*)(SPK + (size_t)4*PLANE);

  prep<<<2056, 256, 0, stream>>>(x, y, qw, kw, vw, pw,
      qg, qb, qm, qv, kg, kb, km, kv, vg, vb, vm, vv, pg, pb, pm, pv,
      wsu, ib);

  gemm_qkv<<<1536, 256, 0, stream>>>(Wq, wsu, ib, SPK);

  attn<<<512, 256, 0, stream>>>(SPK, SPK + (size_t)PLANE, SPK + 2*(size_t)PLANE, S2T);

  gemm_p<<<512, 256, 0, stream>>>(Wq + (size_t)9*WPL, S2T,
      ib + 3*1024, (float*)d_out);
}

// Round 9
// 170.746 us; speedup vs baseline: 1.0233x; 1.0233x over previous
//
#include <hip/hip_runtime.h>
#include <math.h>

#define TBD 8
#define CD  512
#define ND  512
#define PLANE (TBD*CD*ND)   // 2,097,152 elems (u16) per plane
#define WPL   (CD*CD)

typedef unsigned short u16;
typedef unsigned int u32;
typedef _Float16 f16;
typedef __attribute__((ext_vector_type(8))) short bf16x8;
typedef __attribute__((ext_vector_type(8))) _Float16 f16x8;
typedef __attribute__((ext_vector_type(4))) float f32x4;

__device__ __forceinline__ float b2f(u16 u){
  union{u32 i; float f;} x; x.i = ((u32)u) << 16; return x.f;
}
__device__ __forceinline__ u16 f2b(float f){
  u32 u = __builtin_bit_cast(u32, f);
  u += 0x7fffu + ((u >> 16) & 1u);
  return (u16)(u >> 16);
}
__device__ __forceinline__ void async_ld16(const void* g, void* l){
  __builtin_amdgcn_global_load_lds((const __attribute__((address_space(1))) u32*)g,
      (__attribute__((address_space(3))) u32*)l, 16, 0, 0);
}

// ---------------------------------------------------------------------------
// prep (r3..r7-proven, unchanged):
//  [0,1024):   x/y -> 3 exact bf16 split planes each, transposed to [tb][n][c]
//  [1024,2048): 4 W matrices -> 3 bf16 split planes [o][c]
//  [2048,2056): BN inv/bias
// ---------------------------------------------------------------------------
__global__ __launch_bounds__(256) void prep(
    const float* __restrict__ x, const float* __restrict__ y,
    const float* __restrict__ Qw, const float* __restrict__ Kw,
    const float* __restrict__ Vw, const float* __restrict__ Pw,
    const float* __restrict__ Qg, const float* __restrict__ Qb, const float* __restrict__ Qm, const float* __restrict__ Qv,
    const float* __restrict__ Kg, const float* __restrict__ Kb, const float* __restrict__ Km, const float* __restrict__ Kv,
    const float* __restrict__ Vg, const float* __restrict__ Vb, const float* __restrict__ Vm, const float* __restrict__ Vv,
    const float* __restrict__ Pg, const float* __restrict__ Pb, const float* __restrict__ Pm, const float* __restrict__ Pv,
    u16* __restrict__ wsu, float* __restrict__ ib)
{
  const int bx = blockIdx.x, t = threadIdx.x;
  if (bx < 1024) {
    __shared__ __align__(16) float tl[64][68];
    const int inp = bx >> 9, rem = bx & 511;
    const int tb = rem >> 6, tile = rem & 63;
    const int ct = (tile & 7) << 6, nt = (tile >> 3) << 6;
    const float* xg = inp ? y : x;
    #pragma unroll
    for (int r = 0; r < 4; ++r) {
      const int row = (t >> 4) + (r << 4);
      const int col = (t & 15) << 2;
      *(float4*)&tl[row][col] =
          *(const float4*)(xg + ((size_t)(tb*CD + ct + row))*ND + nt + col);
    }
    __syncthreads();
    const int nl = t >> 2, cb = (t & 3) << 4;
    __align__(16) u16 h[3][16];
    #pragma unroll
    for (int j = 0; j < 16; ++j) {
      const float f = tl[cb + j][nl];
      const u16 a = f2b(f);  const float r1 = f - b2f(a);
      const u16 b = f2b(r1); const float r2 = r1 - b2f(b);
      h[0][j] = a; h[1][j] = b; h[2][j] = f2b(r2);
    }
    u16* base = wsu + (size_t)inp*3*PLANE;
    const size_t rowo = ((size_t)tb*ND + nt + nl)*CD + ct + cb;
    #pragma unroll
    for (int s = 0; s < 3; ++s) {
      *(uint4*)(base + (size_t)s*PLANE + rowo)     = *(uint4*)&h[s][0];
      *(uint4*)(base + (size_t)s*PLANE + rowo + 8) = *(uint4*)&h[s][8];
    }
  } else if (bx < 2048) {
    const int b2 = bx - 1024;
    const int mat = b2 >> 8, rr = b2 & 255;
    const float* Wg = (mat==0)?Qw:(mat==1)?Kw:(mat==2)?Vw:Pw;
    const int row = (rr << 1) + (t >> 7);
    const int col = (t & 127) << 2;
    const float4 w = *(const float4*)(Wg + (size_t)row*CD + col);
    const float f[4] = {w.x, w.y, w.z, w.w};
    __align__(8) u16 h[3][4];
    #pragma unroll
    for (int j = 0; j < 4; ++j) {
      const u16 a = f2b(f[j]);  const float r1 = f[j] - b2f(a);
      const u16 b = f2b(r1);    const float r2 = r1 - b2f(b);
      h[0][j] = a; h[1][j] = b; h[2][j] = f2b(r2);
    }
    u16* base = wsu + (size_t)6*PLANE + (size_t)mat*3*WPL;
    #pragma unroll
    for (int s = 0; s < 3; ++s)
      *(uint2*)(base + (size_t)s*WPL + (size_t)row*CD + col) = *(uint2*)&h[s][0];
  } else {
    const int idx = (bx - 2048)*256 + t;
    const int br = idx >> 9, ch = idx & 511;
    const float* G = (br==0)?Qg:(br==1)?Kg:(br==2)?Vg:Pg;
    const float* B = (br==0)?Qb:(br==1)?Kb:(br==2)?Vb:Pb;
    const float* M = (br==0)?Qm:(br==1)?Km:(br==2)?Vm:Pm;
    const float* V = (br==0)?Qv:(br==1)?Kv:(br==2)?Vv:Pv;
    const float inv = G[ch] / sqrtf(V[ch] + 1e-5f);
    ib[br*1024 + ch]       = inv;
    ib[br*1024 + 512 + ch] = B[ch] - M[ch]*inv;
  }
}

// ---------------------------------------------------------------------------
// qkv split-bf16 MFMA GEMM + BN + LIF — r5/r7-proven EXACT structure
// (50.3-52.0 us, MfmaUtil ~31, conflicts 0). 16x16x32 MFMA: its fragment
// read spans all 4 XOR-swizzle k-block slots per instruction (bijective in
// lane>>4), which is what keeps LDS conflict-free; the r8 32x32x16 variant
// only spanned 2 slots/read -> 4.7M conflicts, reverted.
// 1536 blocks: br = bx>>9 selects branch (q:x, k:y, v:y).
// Outputs f16 spikes [tb][c][n] into planes 0/1/2.
// ---------------------------------------------------------------------------
__global__ __launch_bounds__(256) void gemm_qkv(
    const u16* __restrict__ Ab, const u16* __restrict__ Bbp,
    const float* __restrict__ ibp, u16* __restrict__ spk)
{
  const int bx  = blockIdx.x;
  const int idx = bx & 511;
  const int br  = bx >> 9;
  const int tb  = idx & 7;
  const int o0  = ((idx >> 3) & 7) << 6;
  const int n0  = (idx >> 6) << 6;
  const int t    = threadIdx.x;
  const int lane = t & 63, wave = t >> 6;

  const u16* A = Ab + (size_t)br*3*WPL;
  const u16* B = Bbp + (size_t)(br ? 3 : 0)*PLANE;
  const float* IB = ibp + br*1024;

  __shared__ __align__(16) u16 smem[2*3*4*512 + 2*3*4*512];   // 48 KB
  u16* Al = smem;
  u16* Bl = smem + 2*3*4*512;

  const int lr = lane >> 2;
  const int lc = ((lane & 3) ^ ((lane >> 3) & 3)) << 3;

  auto stage = [&](int buf, int c0) {
    #pragma unroll
    for (int j = 0; j < 6; ++j) {
      const int tix = wave*6 + j;
      if (tix < 12) {
        const int s = tix >> 2, ot = tix & 3;
        async_ld16(A + (size_t)s*WPL + (size_t)(o0 + (ot<<4) + lr)*CD + c0 + lc,
                   Al + (((buf*3 + s)*4 + ot) << 9) + (lane << 3));
      } else {
        const int k = tix - 12, s = k >> 2, nt = k & 3;
        async_ld16(B + (size_t)s*PLANE + ((size_t)tb*ND + n0 + (nt<<4) + lr)*CD + c0 + lc,
                   Bl + (((buf*3 + s)*4 + nt) << 9) + (lane << 3));
      }
    }
  };

  f32x4 acc[2][2];
  const f32x4 zero = {0.f, 0.f, 0.f, 0.f};
  acc[0][0] = zero; acc[0][1] = zero; acc[1][0] = zero; acc[1][1] = zero;

  const int otb = (wave >> 1) << 1;
  const int ntb = (wave & 1) << 1;
  const int fo = ((lane & 15) << 5) + ((((lane >> 4) ^ ((lane >> 1) & 3)) & 3) << 3);

  stage(0, 0);
  for (int i = 0; i < 16; ++i) {
    const int buf = i & 1;
    __syncthreads();
    if (i < 15) stage(buf ^ 1, (i + 1) << 5);

    bf16x8 Af[3][2], Bf[3][2];
    #pragma unroll
    for (int s = 0; s < 3; ++s)
      #pragma unroll
      for (int oy = 0; oy < 2; ++oy)
        Af[s][oy] = *(const bf16x8*)(Al + (((buf*3 + s)*4 + otb + oy) << 9) + fo);
    #pragma unroll
    for (int s = 0; s < 3; ++s)
      #pragma unroll
      for (int nx = 0; nx < 2; ++nx)
        Bf[s][nx] = *(const bf16x8*)(Bl + (((buf*3 + s)*4 + ntb + nx) << 9) + fo);

    auto mm = [&](int sa, int sb) {
      #pragma unroll
      for (int oy = 0; oy < 2; ++oy)
        #pragma unroll
        for (int nx = 0; nx < 2; ++nx)
          acc[oy][nx] = __builtin_amdgcn_mfma_f32_16x16x32_bf16(
              Af[sa][oy], Bf[sb][nx], acc[oy][nx], 0, 0, 0);
    };
    mm(0,0); mm(0,1); mm(1,0); mm(1,1); mm(0,2); mm(2,0);
  }

  // r3/r5-proven direct-scatter epilogue. C layout (m89): col=lane&15,
  // row=(lane>>4)*4+reg
  const int rbase = (lane >> 4) << 2;
  const int cl = lane & 15;
  #pragma unroll
  for (int oy = 0; oy < 2; ++oy)
    #pragma unroll
    for (int r = 0; r < 4; ++r) {
      const int ch = o0 + ((otb + oy) << 4) + rbase + r;
      const float inv  = IB[ch];
      const float bias = IB[512 + ch];
      #pragma unroll
      for (int nx = 0; nx < 2; ++nx) {
        const bool sp = (acc[oy][nx][r] * inv + bias >= 2.0f);
        const int n = n0 + ((ntb + nx) << 4) + cl;
        spk[(size_t)br*PLANE + ((size_t)tb*CD + ch)*ND + n] = sp ? (u16)0x3C00 : (u16)0;
      }
    }
}

// ---------------------------------------------------------------------------
// MFMA attention (r5..r7-proven, unchanged).
// ---------------------------------------------------------------------------
__global__ __launch_bounds__(256) void attn(
    const u16* __restrict__ Qs, const u16* __restrict__ Ks,
    const u16* __restrict__ Vs, u16* __restrict__ S2T)
{
  const int tbh = blockIdx.x >> 2;
  const int n0  = (blockIdx.x & 3) << 7;
  const int t = threadIdx.x, lane = t & 63, wave = t >> 6;
  const int tb = tbh >> 4, h = tbh & 15;

  __shared__ __align__(16) u16 Kt[2*8*512];
  __shared__ __align__(16) u16 Vt[2*8*512];
  __shared__ __align__(16) u16 Qg[8*520];
  __shared__ __align__(16) u16 Gt[4*32*40];
  __shared__ __align__(16) u16 Sb[128*40];

  const u16* Kh = Ks + (size_t)tbh*32*ND;
  const u16* Vh = Vs + (size_t)tbh*32*ND;
  const u16* Qh = Qs + (size_t)tbh*32*ND;

  const int lr = lane >> 2;
  const int lc = ((lane & 3) ^ ((lane >> 3) & 3)) << 3;
  const int fo = ((lane & 15) << 5) + ((((lane >> 4) ^ ((lane >> 1) & 3)) & 3) << 3);

  f32x4 g[2][2];
  const f32x4 zero = {0.f, 0.f, 0.f, 0.f};
  g[0][0] = zero; g[0][1] = zero; g[1][0] = zero; g[1][1] = zero;

  for (int half = 0; half < 2; ++half) {
    if (half) __syncthreads();
    #pragma unroll
    for (int j = 0; j < 8; ++j) {
      const int u = wave*8 + j;
      const int mat = u >> 4, dt = (u >> 3) & 1, kc = u & 7;
      const u16* src = (mat ? Vh : Kh) + (size_t)((dt << 4) + lr)*ND + (half << 8) + (kc << 5) + lc;
      u16* dst = (mat ? Vt : Kt) + (((dt << 3) + kc) << 9) + (lane << 3);
      async_ld16(src, dst);
    }
    if (half == 0) {
      #pragma unroll
      for (int j = 0; j < 2; ++j) {
        const int gq = wave*2 + j;
        async_ld16(Qh + (size_t)((gq << 2) + (lane >> 4))*ND + n0 + ((lane & 15) << 3),
                   Qg + gq*520 + (lane << 3));
      }
    }
    __syncthreads();
    for (int kc = 0; kc < 8; ++kc) {
      const f16* kt = (const f16*)Kt;
      const f16* vt = (const f16*)Vt;
      f16x8 ka0 = *(const f16x8*)(kt + (kc << 9) + fo);
      f16x8 ka1 = *(const f16x8*)(kt + ((8 + kc) << 9) + fo);
      f16x8 vb0 = *(const f16x8*)(vt + (kc << 9) + fo);
      f16x8 vb1 = *(const f16x8*)(vt + ((8 + kc) << 9) + fo);
      g[0][0] = __builtin_amdgcn_mfma_f32_16x16x32_f16(ka0, vb0, g[0][0], 0,0,0);
      g[0][1] = __builtin_amdgcn_mfma_f32_16x16x32_f16(ka0, vb1, g[0][1], 0,0,0);
      g[1][0] = __builtin_amdgcn_mfma_f32_16x16x32_f16(ka1, vb0, g[1][0], 0,0,0);
      g[1][1] = __builtin_amdgcn_mfma_f32_16x16x32_f16(ka1, vb1, g[1][1], 0,0,0);
    }
  }

  f16* myG = (f16*)(Gt + wave*(32*40));
  const int rq = (lane >> 4) << 2, cl = lane & 15;
  #pragma unroll
  for (int d1t = 0; d1t < 2; ++d1t)
    #pragma unroll
    for (int d2t = 0; d2t < 2; ++d2t)
      #pragma unroll
      for (int r = 0; r < 4; ++r) {
        const int d1 = (d1t << 4) + rq + r;
        const int d2 = (d2t << 4) + cl;
        myG[d2*40 + d1] = (f16)g[d1t][d2t][r];
      }
  asm volatile("s_waitcnt lgkmcnt(0)" ::: "memory");

  f32x4 o[2][2];
  o[0][0] = zero; o[0][1] = zero; o[1][0] = zero; o[1][1] = zero;
  const f16* ql = (const f16*)Qg;
  const int kg = lane >> 4, n16 = lane & 15;
  #pragma unroll
  for (int ntl = 0; ntl < 2; ++ntl) {
    const int n0w = ((wave << 1) + ntl) << 4;
    f16x8 qb;
    #pragma unroll
    for (int j = 0; j < 8; ++j)
      qb[j] = ql[(2*kg + (j >> 2))*520 + (j & 3)*128 + n0w + n16];
    #pragma unroll
    for (int dd = 0; dd < 2; ++dd) {
      f16x8 ga = *(const f16x8*)(myG + (((dd << 4) + cl)*40) + (kg << 3));
      o[dd][ntl] = __builtin_amdgcn_mfma_f32_16x16x32_f16(ga, qb, o[dd][ntl], 0,0,0);
    }
  }

  #pragma unroll
  for (int dd = 0; dd < 2; ++dd)
    #pragma unroll
    for (int ntl = 0; ntl < 2; ++ntl)
      #pragma unroll
      for (int r = 0; r < 4; ++r) {
        const int n_local = ((wave*2 + ntl) << 4) + cl;
        const int c_local = (dd << 4) + rq + r;
        Sb[n_local*40 + c_local] = (o[dd][ntl][r] >= 8.0f) ? (u16)0x3F80 : (u16)0;
      }
  asm volatile("s_waitcnt lgkmcnt(0)" ::: "memory");

  const int nr = (wave << 5) + (lane >> 1);
  const int cs = (lane & 1) << 4;
  u16* dst = S2T + ((size_t)tb*ND + n0 + nr)*CD + (h << 5) + cs;
  *(uint4*)dst       = *(uint4*)&Sb[nr*40 + cs];
  *(uint4*)(dst + 8) = *(uint4*)&Sb[nr*40 + cs + 8];
}

// ---------------------------------------------------------------------------
// Final gemm, BK=64 (r6/r7-proven): two 16x32 sub-tiles per chunk, 8
// barriers, 64 KB LDS dbuf, grid 512 = 2 blocks/CU all co-resident.
// ---------------------------------------------------------------------------
__global__ __launch_bounds__(256) void gemm_p(
    const u16* __restrict__ Ab, const u16* __restrict__ Bb,
    const float* __restrict__ IB, float* __restrict__ outf)
{
  const int idx = blockIdx.x;
  const int tb  = idx & 7;
  const int o0  = ((idx >> 3) & 7) << 6;
  const int n0  = (idx >> 6) << 6;
  const int t    = threadIdx.x;
  const int lane = t & 63, wave = t >> 6;

  __shared__ __align__(16) u16 smem[2*32*512];   // 64 KB

  const int lr = lane >> 2;
  const int lc = ((lane & 3) ^ ((lane >> 3) & 3)) << 3;
  const int otb = (wave >> 1) << 1;
  const int ntb = (wave & 1) << 1;
  const int fo = ((lane & 15) << 5) + ((((lane >> 4) ^ ((lane >> 1) & 3)) & 3) << 3);

  auto stage = [&](int buf, int c0) {
    #pragma unroll
    for (int j = 0; j < 8; ++j) {
      const int tix  = wave*8 + j;
      const int ksub = tix >> 4, slot = tix & 15;
      const int cc = c0 + (ksub << 5);
      const u16* g;
      if (slot < 12) {
        const int s = slot >> 2, ot = slot & 3;
        g = Ab + (size_t)s*WPL + (size_t)(o0 + (ot<<4) + lr)*CD + cc + lc;
      } else {
        const int nt = slot - 12;
        g = Bb + ((size_t)tb*ND + n0 + (nt<<4) + lr)*CD + cc + lc;
      }
      async_ld16(g, smem + (((size_t)buf*32 + tix) << 9) + (lane << 3));
    }
  };

  f32x4 acc[2][2];
  const f32x4 zero = {0.f, 0.f, 0.f, 0.f};
  acc[0][0] = zero; acc[0][1] = zero; acc[1][0] = zero; acc[1][1] = zero;

  stage(0, 0);
  for (int i = 0; i < 8; ++i) {
    const int buf = i & 1;
    __syncthreads();
    if (i < 7) stage(buf ^ 1, (i + 1) << 6);

    #pragma unroll
    for (int ksub = 0; ksub < 2; ++ksub) {
      const int base = (buf*32 + ksub*16) << 9;
      bf16x8 Af[3][2], Bf[2];
      #pragma unroll
      for (int s = 0; s < 3; ++s)
        #pragma unroll
        for (int oy = 0; oy < 2; ++oy)
          Af[s][oy] = *(const bf16x8*)(smem + base + ((s*4 + otb + oy) << 9) + fo);
      #pragma unroll
      for (int nx = 0; nx < 2; ++nx)
        Bf[nx] = *(const bf16x8*)(smem + base + ((12 + ntb + nx) << 9) + fo);

      #pragma unroll
      for (int s = 0; s < 3; ++s)
        #pragma unroll
        for (int oy = 0; oy < 2; ++oy)
          #pragma unroll
          for (int nx = 0; nx < 2; ++nx)
            acc[oy][nx] = __builtin_amdgcn_mfma_f32_16x16x32_bf16(
                Af[s][oy], Bf[nx], acc[oy][nx], 0, 0, 0);
    }
  }

  const int rbase = (lane >> 4) << 2;
  const int cl = lane & 15;
  #pragma unroll
  for (int oy = 0; oy < 2; ++oy)
    #pragma unroll
    for (int r = 0; r < 4; ++r) {
      const int ch = o0 + ((otb + oy) << 4) + rbase + r;
      const float inv  = IB[ch];
      const float bias = IB[512 + ch];
      #pragma unroll
      for (int nx = 0; nx < 2; ++nx) {
        const bool sp = (acc[oy][nx][r] * inv + bias >= 2.0f);
        const int n = n0 + ((ntb + nx) << 4) + cl;
        outf[((size_t)tb*CD + ch)*ND + n] = sp ? 1.0f : 0.0f;
      }
    }
}

// ---------------------------------------------------------------------------
extern "C" void kernel_launch(void* const* d_in, const int* in_sizes, int n_in,
                              void* d_out, int out_size, void* d_ws, size_t ws_size,
                              hipStream_t stream)
{
  const float* x  = (const float*)d_in[0];
  const float* y  = (const float*)d_in[1];
  const float* qw = (const float*)d_in[2];
  const float* qg = (const float*)d_in[3];
  const float* qb = (const float*)d_in[4];
  const float* qm = (const float*)d_in[5];
  const float* qv = (const float*)d_in[6];
  const float* kw = (const float*)d_in[7];
  const float* kg = (const float*)d_in[8];
  const float* kb = (const float*)d_in[9];
  const float* km = (const float*)d_in[10];
  const float* kv = (const float*)d_in[11];
  const float* vw = (const float*)d_in[12];
  const float* vg = (const float*)d_in[13];
  const float* vb = (const float*)d_in[14];
  const float* vm = (const float*)d_in[15];
  const float* vv = (const float*)d_in[16];
  const float* pw = (const float*)d_in[17];
  const float* pg = (const float*)d_in[18];
  const float* pb = (const float*)d_in[19];
  const float* pm = (const float*)d_in[20];
  const float* pv = (const float*)d_in[21];

  u16* wsu = (u16*)d_ws;
  // layout (u16): xS[3] | yS[3] | W[4][3] | Q,K,V spikes [c][n] | S2T | ib
  u16* Wq   = wsu + (size_t)6*PLANE;
  u16* SPK  = wsu + (size_t)6*PLANE + 12*WPL;
  u16* S2T  = SPK + (size_t)3*PLANE;
  float* ib = (float*)(SPK + (size_t)4*PLANE);

  prep<<<2056, 256, 0, stream>>>(x, y, qw, kw, vw, pw,
      qg, qb, qm, qv, kg, kb, km, kv, vg, vb, vm, vv, pg, pb, pm, pv,
      wsu, ib);

  gemm_qkv<<<1536, 256, 0, stream>>>(Wq, wsu, ib, SPK);

  attn<<<512, 256, 0, stream>>>(SPK, SPK + (size_t)PLANE, SPK + 2*(size_t)PLANE, S2T);

  gemm_p<<<512, 256, 0, stream>>>(Wq + (size_t)9*WPL, S2T,
      ib + 3*1024, (float*)d_out);
}